// Round 8
// baseline (651.872 us; speedup 1.0000x reference)
//
#include <hip/hip_runtime.h>
#include <hip/hip_bf16.h>

// CLIP loss: B=8192, D=1024, temp=0.5.
// loss = mean_i [ 0.5*(log sum_j exp(s_ij) + log sum_j exp(s_ji)) - s_ii ],
// s = (zi_n @ zj_n^T) * 2.  |s| <= 2 -> exp safe, no max trick.
//
// R8: fp8 MX GEMM sized for the 128-VGPR cap (R6/R7 spilled: scaled-MFMA acc
// lives in arch VGPRs; 128-reg acc + operands >> cap -> 1 GB scratch).
// Tile 256(M) x 128(N), BK=64, grid 2048, 8 waves (2M x 4N), per-wave 128x32
// = acc[4] f32x16 = 64 regs; ~105 total -> fits 128 (__launch_bounds__(512,4)).
// LDS 48 KB tiles + 5 KB reduce bufs -> 2 blocks/CU co-resident: second block
// fills barrier/stage stalls (the overlap my 1-block/CU schedules never got).
// Counted vmcnt(3) (3 loads/thread/tile), 2 barriers/tile, 16B-chunk swizzle
// cphys = c ^ ((row>>1)&3) on both sides (verified 0-conflict).
//
// ws: [0,8M) zi8 (x2 temp folded), [8M,16M) zj8, [16M,18M) rp[64][8192],
//     [18M,19M) cp[32][8192], [19M,+32K) dg[8192], then part[32].

using f32x16 = __attribute__((ext_vector_type(16))) float;
using i32x8  = __attribute__((ext_vector_type(8))) int;
using i32x4  = __attribute__((ext_vector_type(4))) int;

#define USCL 0x7F7F7F7Fu   // E8M0 = 127 -> scale 1.0 in every byte

__device__ __forceinline__ void async16(const unsigned char* g, unsigned char* l) {
    __builtin_amdgcn_global_load_lds(
        (const __attribute__((address_space(1))) void*)g,
        (__attribute__((address_space(3))) void*)l, 16, 0, 0);
}

// ---- kernel 1: row-normalize fp32 -> fp8 e4m3, extra scale folded ----
__global__ __launch_bounds__(256) void clip_norm_k(const float* __restrict__ in,
                                                   unsigned int* __restrict__ out,
                                                   float extra) {
    int row = blockIdx.x;
    const float4* ip = reinterpret_cast<const float4*>(in + (size_t)row * 1024);
    float4 v = ip[threadIdx.x];
    float ss = v.x * v.x + v.y * v.y + v.z * v.z + v.w * v.w;
    #pragma unroll
    for (int o = 1; o < 64; o <<= 1) ss += __shfl_xor(ss, o);
    __shared__ float sb[4];
    if ((threadIdx.x & 63) == 0) sb[threadIdx.x >> 6] = ss;
    __syncthreads();
    float tot = sb[0] + sb[1] + sb[2] + sb[3];
    float scl = extra / fmaxf(sqrtf(tot), 1e-12f);
    int p = __builtin_amdgcn_cvt_pk_fp8_f32(v.x * scl, v.y * scl, 0, false);
    p = __builtin_amdgcn_cvt_pk_fp8_f32(v.z * scl, v.w * scl, p, true);
    out[(size_t)row * 256 + threadIdx.x] = (unsigned int)p;
}

// Read a 32B fp8 fragment (row = l&31 within frag, k-half h = l>>5).
__device__ __forceinline__ i32x8 ldfrag(const unsigned char* buf, int row, int h) {
    int c0 = (2 * h) ^ ((row >> 1) & 3);
    i32x4 lo = *reinterpret_cast<const i32x4*>(buf + row * 64 + c0 * 16);
    i32x4 hi = *reinterpret_cast<const i32x4*>(buf + row * 64 + (c0 ^ 1) * 16);
    i32x8 r;
    r[0] = lo[0]; r[1] = lo[1]; r[2] = lo[2]; r[3] = lo[3];
    r[4] = hi[0]; r[5] = hi[1]; r[6] = hi[2]; r[7] = hi[3];
    return r;
}

__global__ __launch_bounds__(512, 4) void clip_gemm_k(
    const unsigned char* __restrict__ A,   // zi8 [8192][1024]
    const unsigned char* __restrict__ Bm,  // zj8 [8192][1024]
    float* __restrict__ rp, float* __restrict__ cp, float* __restrict__ dg) {
    __shared__ unsigned char tile[2 * 24576];   // buf: {A 16K, B 8K} x2
    __shared__ float rbuf[4][256];
    __shared__ float cbuf[2][128];

    // XCD stripe swizzle: 2048 blocks, 2048 % 8 == 0.
    const int swz = (blockIdx.x & 7) * 256 + (blockIdx.x >> 3);
    const int bi = swz >> 6;                 // 0..31  (256-row M tile)
    const int bj = swz & 63;                 // 0..63  (128-row N tile)
    const int tid = threadIdx.x;
    const int l = tid & 63, w = tid >> 6;
    const int wm = w >> 2, wn = w & 3;       // 2M x 4N wave grid
    const int lane31 = l & 31, h = l >> 5;

    f32x16 acc[4] = {};                      // fm 0..3 (rows wm*128+fm*32+..)

    const unsigned char* Ag = A + (size_t)(bi * 256) * 1024;
    const unsigned char* Bg = Bm + (size_t)(bj * 128) * 1024;

    unsigned char* bA0 = tile;               unsigned char* bB0 = tile + 16384;
    unsigned char* bA1 = tile + 24576;       unsigned char* bB1 = tile + 40960;

    // per-thread staging offsets (row, chunk are thread-constants)
    int r0 = tid >> 2;
    int c0g = (tid & 3) ^ ((r0 >> 1) & 3);
    const int offA0 = r0 * 1024 + c0g * 16;              // A sweep 0 (rows 0..127)
    int r1 = 128 + r0;
    int c1g = (tid & 3) ^ ((r1 >> 1) & 3);
    const int offA1 = r1 * 1024 + c1g * 16;              // A sweep 1 (rows 128..255)
    const int offB = offA0;                              // B rows 0..127: same form
    const int ldso = tid * 16;

#define STAGE(ktB, bufA, bufB)                                   \
    async16(Ag + (ktB) + offA0, (bufA) + ldso);                  \
    async16(Ag + (ktB) + offA1, (bufA) + 8192 + ldso);           \
    async16(Bg + (ktB) + offB,  (bufB) + ldso);

    // prologue: stage tiles 0,1; wait tile 0 (tile1's 3 outstanding)
    STAGE(0, bA0, bB0)
    STAGE(64, bA1, bB1)
    asm volatile("s_waitcnt vmcnt(3)" ::: "memory");
    __builtin_amdgcn_s_barrier();
    __builtin_amdgcn_sched_barrier(0);

    for (int t = 0; t < 16; ++t) {
        const unsigned char* Ac = (t & 1) ? bA1 : bA0;
        const unsigned char* Bc = (t & 1) ? bB1 : bB0;
        unsigned char* Asg = (t & 1) ? bA1 : bA0;
        unsigned char* Bsg = (t & 1) ? bB1 : bB0;

        i32x8 bfr = ldfrag(Bc, wn * 32 + lane31, h);
        #pragma unroll
        for (int fm = 0; fm < 4; ++fm) {
            i32x8 af = ldfrag(Ac, wm * 128 + fm * 32 + lane31, h);
            acc[fm] = __builtin_amdgcn_mfma_scale_f32_32x32x64_f8f6f4(
                af, bfr, acc[fm], 0, 0, 0, USCL, 0, USCL);
        }

        asm volatile("s_waitcnt lgkmcnt(0)" ::: "memory");
        __builtin_amdgcn_s_barrier();        // all waves done reading this buf
        if (t <= 13) {
            STAGE((t + 2) * 64, Asg, Bsg)
            asm volatile("s_waitcnt vmcnt(3)" ::: "memory");   // t+1 landed
        } else if (t == 14) {
            asm volatile("s_waitcnt vmcnt(0)" ::: "memory");   // t=15 landed
        }
        if (t <= 14) {
            __builtin_amdgcn_s_barrier();
            __builtin_amdgcn_sched_barrier(0);
        }
    }
#undef STAGE

    // ---- epilogue ----
    // 32x32 C/D layout: col = l&31, row = (reg&3) + 8*(reg>>2) + 4*(l>>5).
    // Wave rows: wm*128 + fm*32 + rif (0..255); wave cols: wn*32 + lane31.
    if (bi == (bj >> 1)) {
        const int rowoff = (bj & 1) * 128;
        #pragma unroll
        for (int fm = 0; fm < 4; ++fm)
            #pragma unroll
            for (int reg = 0; reg < 16; ++reg) {
                int rif = (reg & 3) + 8 * (reg >> 2) + 4 * h;
                int lrow = wm * 128 + fm * 32 + rif;
                if (wn * 32 + lane31 == lrow - rowoff)
                    dg[bi * 256 + lrow] = acc[fm][reg];
            }
    }

    #pragma unroll
    for (int fm = 0; fm < 4; ++fm)
        #pragma unroll
        for (int reg = 0; reg < 16; ++reg)
            acc[fm][reg] = exp2f(acc[fm][reg] * 1.44269504f);

    // row sums over this wave's 32 cols -> rbuf[wn][row]
    #pragma unroll
    for (int fm = 0; fm < 4; ++fm) {
        #pragma unroll
        for (int reg = 0; reg < 16; ++reg) {
            float v = acc[fm][reg];
            v += __shfl_xor(v, 1);
            v += __shfl_xor(v, 2);
            v += __shfl_xor(v, 4);
            v += __shfl_xor(v, 8);
            v += __shfl_xor(v, 16);
            if (lane31 == 0) {
                int rif = (reg & 3) + 8 * (reg >> 2) + 4 * h;
                rbuf[wn][wm * 128 + fm * 32 + rif] = v;
            }
        }
    }
    // col sums over this wave's 128 rows -> cbuf[wm][col]
    {
        float v = 0.f;
        #pragma unroll
        for (int fm = 0; fm < 4; ++fm)
            #pragma unroll
            for (int reg = 0; reg < 16; ++reg)
                v += acc[fm][reg];
        v += __shfl_xor(v, 32);
        if (h == 0) cbuf[wm][wn * 32 + lane31] = v;
    }
    __syncthreads();
    if (tid < 256)
        rp[(size_t)bj * 8192 + bi * 256 + tid] =
            rbuf[0][tid] + rbuf[1][tid] + rbuf[2][tid] + rbuf[3][tid];
    if (tid < 128)
        cp[(size_t)bi * 8192 + bj * 128 + tid] = cbuf[0][tid] + cbuf[1][tid];
}

// ---- per-row logs, block partial sums ----
__global__ __launch_bounds__(256) void clip_fin1_k(const float* __restrict__ rp,
                                                   const float* __restrict__ cp,
                                                   const float* __restrict__ dg,
                                                   float* __restrict__ part) {
    int i = blockIdx.x * 256 + threadIdx.x;
    float rs = 0.f, cs = 0.f;
    #pragma unroll 8
    for (int b = 0; b < 64; ++b) rs += rp[(size_t)b * 8192 + i];
    #pragma unroll 8
    for (int b = 0; b < 32; ++b) cs += cp[(size_t)b * 8192 + i];
    float c = 0.5f * (logf(rs) + logf(cs)) - dg[i];
    #pragma unroll
    for (int o = 1; o < 64; o <<= 1) c += __shfl_xor(c, o);
    __shared__ float sb[4];
    if ((threadIdx.x & 63) == 0) sb[threadIdx.x >> 6] = c;
    __syncthreads();
    if (threadIdx.x == 0) part[blockIdx.x] = sb[0] + sb[1] + sb[2] + sb[3];
}

__global__ void clip_fin2_k(const float* __restrict__ part, float* __restrict__ out) {
    float v = (threadIdx.x < 32) ? part[threadIdx.x] : 0.f;
    #pragma unroll
    for (int o = 1; o < 64; o <<= 1) v += __shfl_xor(v, o);
    if (threadIdx.x == 0) out[0] = v * (1.f / 8192.f);
}

extern "C" void kernel_launch(void* const* d_in, const int* in_sizes, int n_in,
                              void* d_out, int out_size, void* d_ws, size_t ws_size,
                              hipStream_t stream) {
    const float* zi = (const float*)d_in[0];
    const float* zj = (const float*)d_in[1];
    float* out = (float*)d_out;
    char* ws = (char*)d_ws;

    unsigned int* zi8 = (unsigned int*)(ws);
    unsigned int* zj8 = (unsigned int*)(ws + (size_t)8 * 1024 * 1024);
    float* rp   = (float*)(ws + (size_t)16 * 1024 * 1024);   // 2 MB (64 panels)
    float* cp   = (float*)(ws + (size_t)18 * 1024 * 1024);   // 1 MB (32 panels)
    float* dg   = (float*)(ws + (size_t)19 * 1024 * 1024);
    float* part = (float*)(ws + (size_t)19 * 1024 * 1024 + 32768);

    clip_norm_k<<<8192, 256, 0, stream>>>(zi, zi8, 2.0f);   // temp x2 folded into zi
    clip_norm_k<<<8192, 256, 0, stream>>>(zj, zj8, 1.0f);
    clip_gemm_k<<<2048, 512, 0, stream>>>((const unsigned char*)zi8,
                                          (const unsigned char*)zj8, rp, cp, dg);
    clip_fin1_k<<<32, 256, 0, stream>>>(rp, cp, dg, part);
    clip_fin2_k<<<1, 64, 0, stream>>>(part, out);
}

// Round 9
// 137.893 us; speedup vs baseline: 4.7274x; 4.7274x over previous
//
#include <hip/hip_runtime.h>
#include <hip/hip_bf16.h>

// CLIP loss: B=8192, D=1024, temp=0.5.
// loss = mean_i [ 0.5*(log sum_j exp(s_ij) + log sum_j exp(s_ji)) - s_ii ],
// s = (zi_n @ zj_n^T) * 2.  |s| <= 2 -> exp safe, no max trick.
//
// R9: m148 recipe. mfma_scale_f32_16x16x128_f8f6f4 (acc f32x4 -- the tuple
// shape that never spilled; R6-R8's f32x16 32x32 acc always spilled).
// 128x128 tile, 256 thr, 4 waves (2x2), per-wave 64x64 = acc[4][4] f32x4.
// BK=128 fp8 bytes, double-buffer A/B [128][128B] (64 KB) -> 2 blocks/CU
// (R1/R8 evidence: multi-block/CU doubles staging throughput vs 1 block).
// Counted vmcnt(8) (8 loads/thread/tile), loose interior, no order pinning.
// Swizzle: 16B-chunk cphys = clog ^ (row&7) both sides -> <=2-way (free).
//
// ws: [0,8M) zi8 (x2 temp folded), [8M,16M) zj8, [16M,18M) rp[64][8192],
//     [18M,20M) cp[64][8192], [20M,+32K) dg[8192], then part[32].

using f32x4 = __attribute__((ext_vector_type(4))) float;
using i32x8 = __attribute__((ext_vector_type(8))) int;
using i32x4 = __attribute__((ext_vector_type(4))) int;

#define USCL 0x7F7F7F7Fu   // E8M0 = 127 -> scale 1.0 in every byte

__device__ __forceinline__ void async16(const unsigned char* g, unsigned char* l) {
    __builtin_amdgcn_global_load_lds(
        (const __attribute__((address_space(1))) void*)g,
        (__attribute__((address_space(3))) void*)l, 16, 0, 0);
}

// ---- kernel 1: row-normalize fp32 -> fp8 e4m3, extra scale folded ----
__global__ __launch_bounds__(256) void clip_norm_k(const float* __restrict__ in,
                                                   unsigned int* __restrict__ out,
                                                   float extra) {
    int row = blockIdx.x;
    const float4* ip = reinterpret_cast<const float4*>(in + (size_t)row * 1024);
    float4 v = ip[threadIdx.x];
    float ss = v.x * v.x + v.y * v.y + v.z * v.z + v.w * v.w;
    #pragma unroll
    for (int o = 1; o < 64; o <<= 1) ss += __shfl_xor(ss, o);
    __shared__ float sb[4];
    if ((threadIdx.x & 63) == 0) sb[threadIdx.x >> 6] = ss;
    __syncthreads();
    float tot = sb[0] + sb[1] + sb[2] + sb[3];
    float scl = extra / fmaxf(sqrtf(tot), 1e-12f);
    int p = __builtin_amdgcn_cvt_pk_fp8_f32(v.x * scl, v.y * scl, 0, false);
    p = __builtin_amdgcn_cvt_pk_fp8_f32(v.z * scl, v.w * scl, p, true);
    out[(size_t)row * 256 + threadIdx.x] = (unsigned int)p;
}

// Read a 32B fp8 A/B fragment for 16x16x128: row in tile, khi = l>>4 (0..3)
// covers k = khi*32 .. khi*32+31. LDS row = 8 chunks of 16B, phys = log^(row&7).
__device__ __forceinline__ i32x8 ldfrag(const unsigned char* buf, int row, int khi) {
    int p0 = (2 * khi) ^ (row & 7);
    int p1 = (2 * khi + 1) ^ (row & 7);
    i32x4 lo = *reinterpret_cast<const i32x4*>(buf + row * 128 + p0 * 16);
    i32x4 hi = *reinterpret_cast<const i32x4*>(buf + row * 128 + p1 * 16);
    i32x8 r;
    r[0] = lo[0]; r[1] = lo[1]; r[2] = lo[2]; r[3] = lo[3];
    r[4] = hi[0]; r[5] = hi[1]; r[6] = hi[2]; r[7] = hi[3];
    return r;
}

__global__ __launch_bounds__(256, 2) void clip_gemm_k(
    const unsigned char* __restrict__ A,   // zi8 [8192][1024]
    const unsigned char* __restrict__ Bm,  // zj8 [8192][1024]
    float* __restrict__ rp, float* __restrict__ cp, float* __restrict__ dg) {
    __shared__ unsigned char bA0[16384], bB0[16384], bA1[16384], bB1[16384];
    __shared__ float rbuf[2][128];
    __shared__ float cbuf[2][128];

    // XCD stripe swizzle: 4096 blocks, 4096 % 8 == 0.
    const int swz = (blockIdx.x & 7) * 512 + (blockIdx.x >> 3);
    const int bi = swz >> 6, bj = swz & 63;  // 64x64 tiles of 128x128
    const int tid = threadIdx.x;
    const int l = tid & 63, w = tid >> 6;
    const int wm = w >> 1, wn = w & 1;       // 2x2 wave grid, per-wave 64x64
    const int llo = l & 15, khi = l >> 4;

    f32x4 acc[4][4] = {};

    const unsigned char* Ag = A + (size_t)(bi * 128) * 1024;
    const unsigned char* Bg = Bm + (size_t)(bj * 128) * 1024;

    // per-thread staging offsets (4 sweeps x 256 thr x 16B = one [128][128B] buf)
    int srow[4], soff[4];
    #pragma unroll
    for (int s = 0; s < 4; ++s) {
        int idx = s * 256 + tid;
        srow[s] = idx >> 3;
        int clog = idx & 7;
        soff[s] = srow[s] * 1024 + ((clog ^ (srow[s] & 7)) * 16);
    }
    const int ldst = tid * 16;   // linear dest within each sweep block

#define STAGE(ktB, bufA, bufB)                                            \
    _Pragma("unroll") for (int s = 0; s < 4; ++s)                         \
        async16(Ag + (ktB) + soff[s], (bufA) + s * 4096 + ldst);          \
    _Pragma("unroll") for (int s = 0; s < 4; ++s)                         \
        async16(Bg + (ktB) + soff[s], (bufB) + s * 4096 + ldst);

    // prologue: stage tiles 0,1; wait tile 0 (tile1's 8 outstanding)
    STAGE(0, bA0, bB0)
    STAGE(128, bA1, bB1)
    asm volatile("s_waitcnt vmcnt(8)" ::: "memory");
    __builtin_amdgcn_s_barrier();
    __builtin_amdgcn_sched_barrier(0);

    for (int t = 0; t < 8; ++t) {
        const unsigned char* Ac = (t & 1) ? bA1 : bA0;
        const unsigned char* Bc = (t & 1) ? bB1 : bB0;
        unsigned char* Asg = (t & 1) ? bA1 : bA0;
        unsigned char* Bsg = (t & 1) ? bB1 : bB0;

        i32x8 af[4], bfr[4];
        #pragma unroll
        for (int m = 0; m < 4; ++m)
            af[m] = ldfrag(Ac, wm * 64 + m * 16 + llo, khi);
        #pragma unroll
        for (int n = 0; n < 4; ++n)
            bfr[n] = ldfrag(Bc, wn * 64 + n * 16 + llo, khi);
        #pragma unroll
        for (int m = 0; m < 4; ++m)
            #pragma unroll
            for (int n = 0; n < 4; ++n)
                acc[m][n] = __builtin_amdgcn_mfma_scale_f32_16x16x128_f8f6f4(
                    af[m], bfr[n], acc[m][n], 0, 0, 0, USCL, 0, USCL);

        asm volatile("s_waitcnt lgkmcnt(0)" ::: "memory");
        __builtin_amdgcn_s_barrier();        // all waves done reading this buf
        if (t <= 5) {
            STAGE((t + 2) * 128, Asg, Bsg)
            asm volatile("s_waitcnt vmcnt(8)" ::: "memory");   // t+1 landed
        } else if (t == 6) {
            asm volatile("s_waitcnt vmcnt(0)" ::: "memory");   // t=7 landed
        }
        if (t <= 6) {
            __builtin_amdgcn_s_barrier();
            __builtin_amdgcn_sched_barrier(0);
        }
    }
#undef STAGE

    // ---- epilogue (R1-verified 16x16 C/D mapping: col=llo, row=khi*4+reg) ----
    if (bi == bj && wm == wn) {
        #pragma unroll
        for (int m = 0; m < 4; ++m)
            #pragma unroll
            for (int r = 0; r < 4; ++r)
                if (khi * 4 + r == llo)
                    dg[bi * 128 + wm * 64 + m * 16 + llo] = acc[m][m][r];
    }

    #pragma unroll
    for (int m = 0; m < 4; ++m)
        #pragma unroll
        for (int n = 0; n < 4; ++n)
            #pragma unroll
            for (int r = 0; r < 4; ++r)
                acc[m][n][r] = exp2f(acc[m][n][r] * 1.44269504f);

    // row sums over this wave's 64 cols
    #pragma unroll
    for (int m = 0; m < 4; ++m) {
        #pragma unroll
        for (int r = 0; r < 4; ++r) {
            float v = acc[m][0][r] + acc[m][1][r] + acc[m][2][r] + acc[m][3][r];
            v += __shfl_xor(v, 1);
            v += __shfl_xor(v, 2);
            v += __shfl_xor(v, 4);
            v += __shfl_xor(v, 8);
            if (llo == 0) rbuf[wn][wm * 64 + m * 16 + khi * 4 + r] = v;
        }
    }
    // col sums over this wave's 64 rows
    #pragma unroll
    for (int n = 0; n < 4; ++n) {
        float v = 0.f;
        #pragma unroll
        for (int m = 0; m < 4; ++m)
            v += acc[m][n][0] + acc[m][n][1] + acc[m][n][2] + acc[m][n][3];
        v += __shfl_xor(v, 16);
        v += __shfl_xor(v, 32);
        if (khi == 0) cbuf[wm][wn * 64 + n * 16 + llo] = v;
    }
    __syncthreads();
    if (tid < 128) {
        rp[(size_t)bj * 8192 + bi * 128 + tid] = rbuf[0][tid] + rbuf[1][tid];
        cp[(size_t)bi * 8192 + bj * 128 + tid] = cbuf[0][tid] + cbuf[1][tid];
    }
}

// ---- per-row logs, block partial sums ----
__global__ __launch_bounds__(256) void clip_fin1_k(const float* __restrict__ rp,
                                                   const float* __restrict__ cp,
                                                   const float* __restrict__ dg,
                                                   float* __restrict__ part) {
    int i = blockIdx.x * 256 + threadIdx.x;
    float rs = 0.f, cs = 0.f;
    #pragma unroll 8
    for (int b = 0; b < 64; ++b) rs += rp[(size_t)b * 8192 + i];
    #pragma unroll 8
    for (int b = 0; b < 64; ++b) cs += cp[(size_t)b * 8192 + i];
    float c = 0.5f * (logf(rs) + logf(cs)) - dg[i];
    #pragma unroll
    for (int o = 1; o < 64; o <<= 1) c += __shfl_xor(c, o);
    __shared__ float sb[4];
    if ((threadIdx.x & 63) == 0) sb[threadIdx.x >> 6] = c;
    __syncthreads();
    if (threadIdx.x == 0) part[blockIdx.x] = sb[0] + sb[1] + sb[2] + sb[3];
}

__global__ void clip_fin2_k(const float* __restrict__ part, float* __restrict__ out) {
    float v = (threadIdx.x < 32) ? part[threadIdx.x] : 0.f;
    #pragma unroll
    for (int o = 1; o < 64; o <<= 1) v += __shfl_xor(v, o);
    if (threadIdx.x == 0) out[0] = v * (1.f / 8192.f);
}

extern "C" void kernel_launch(void* const* d_in, const int* in_sizes, int n_in,
                              void* d_out, int out_size, void* d_ws, size_t ws_size,
                              hipStream_t stream) {
    const float* zi = (const float*)d_in[0];
    const float* zj = (const float*)d_in[1];
    float* out = (float*)d_out;
    char* ws = (char*)d_ws;

    unsigned int* zi8 = (unsigned int*)(ws);
    unsigned int* zj8 = (unsigned int*)(ws + (size_t)8 * 1024 * 1024);
    float* rp   = (float*)(ws + (size_t)16 * 1024 * 1024);   // 2 MB (64 panels)
    float* cp   = (float*)(ws + (size_t)18 * 1024 * 1024);   // 2 MB (64 panels)
    float* dg   = (float*)(ws + (size_t)20 * 1024 * 1024);
    float* part = (float*)(ws + (size_t)20 * 1024 * 1024 + 32768);

    clip_norm_k<<<8192, 256, 0, stream>>>(zi, zi8, 2.0f);   // temp x2 folded into zi
    clip_norm_k<<<8192, 256, 0, stream>>>(zj, zj8, 1.0f);
    clip_gemm_k<<<4096, 256, 0, stream>>>((const unsigned char*)zi8,
                                          (const unsigned char*)zj8, rp, cp, dg);
    clip_fin1_k<<<32, 256, 0, stream>>>(rp, cp, dg, part);
    clip_fin2_k<<<1, 64, 0, stream>>>(part, out);
}

// Round 10
// 128.995 us; speedup vs baseline: 5.0535x; 1.0690x over previous
//
#include <hip/hip_runtime.h>
#include <hip/hip_bf16.h>

// CLIP loss: B=8192, D=1024, temp=0.5.
// loss = mean_i [ 0.5*(log sum_j exp(s_ij) + log sum_j exp(s_ji)) - s_ii ],
// s = (zi_n @ zj_n^T) * 2.  |s| <= 2 -> exp safe, no max trick.
//
// R10 = R9 + L2-supertile swizzle. R9's binder candidate: FETCH 266MB @
// 2 TB/s L2-miss traffic (per-XCD B working set 8MB > 4MB L2 -> thrash).
// New mapping: XCD c owns bi in [8c,8c+8) (A 1MB hot); its 512 blocks run
// as 8 temporal supertiles of 64 = 8bi x 8bj, so one co-resident generation
// (32CU x 2blk) = one supertile = 2MB L2 working set. Bijective.
// GEMM core unchanged from R9 (mfma_scale 16x16x128, acc f32x4, no spill).
//
// ws: [0,8M) zi8 (x2 temp folded), [8M,16M) zj8, [16M,18M) rp[64][8192],
//     [18M,20M) cp[64][8192], [20M,+32K) dg[8192], then part[32].

using f32x4 = __attribute__((ext_vector_type(4))) float;
using i32x8 = __attribute__((ext_vector_type(8))) int;
using i32x4 = __attribute__((ext_vector_type(4))) int;

#define USCL 0x7F7F7F7Fu   // E8M0 = 127 -> scale 1.0 in every byte

__device__ __forceinline__ void async16(const unsigned char* g, unsigned char* l) {
    __builtin_amdgcn_global_load_lds(
        (const __attribute__((address_space(1))) void*)g,
        (__attribute__((address_space(3))) void*)l, 16, 0, 0);
}

// ---- kernel 1: row-normalize fp32 -> fp8 e4m3, extra scale folded ----
__global__ __launch_bounds__(256) void clip_norm_k(const float* __restrict__ in,
                                                   unsigned int* __restrict__ out,
                                                   float extra) {
    int row = blockIdx.x;
    const float4* ip = reinterpret_cast<const float4*>(in + (size_t)row * 1024);
    float4 v = ip[threadIdx.x];
    float ss = v.x * v.x + v.y * v.y + v.z * v.z + v.w * v.w;
    #pragma unroll
    for (int o = 1; o < 64; o <<= 1) ss += __shfl_xor(ss, o);
    __shared__ float sb[4];
    if ((threadIdx.x & 63) == 0) sb[threadIdx.x >> 6] = ss;
    __syncthreads();
    float tot = sb[0] + sb[1] + sb[2] + sb[3];
    float scl = extra / fmaxf(sqrtf(tot), 1e-12f);
    int p = __builtin_amdgcn_cvt_pk_fp8_f32(v.x * scl, v.y * scl, 0, false);
    p = __builtin_amdgcn_cvt_pk_fp8_f32(v.z * scl, v.w * scl, p, true);
    out[(size_t)row * 256 + threadIdx.x] = (unsigned int)p;
}

// Read a 32B fp8 A/B fragment for 16x16x128: row in tile, khi = l>>4 (0..3)
// covers k = khi*32 .. khi*32+31. LDS row = 8 chunks of 16B, phys = log^(row&7).
__device__ __forceinline__ i32x8 ldfrag(const unsigned char* buf, int row, int khi) {
    int p0 = (2 * khi) ^ (row & 7);
    int p1 = (2 * khi + 1) ^ (row & 7);
    i32x4 lo = *reinterpret_cast<const i32x4*>(buf + row * 128 + p0 * 16);
    i32x4 hi = *reinterpret_cast<const i32x4*>(buf + row * 128 + p1 * 16);
    i32x8 r;
    r[0] = lo[0]; r[1] = lo[1]; r[2] = lo[2]; r[3] = lo[3];
    r[4] = hi[0]; r[5] = hi[1]; r[6] = hi[2]; r[7] = hi[3];
    return r;
}

__global__ __launch_bounds__(256, 2) void clip_gemm_k(
    const unsigned char* __restrict__ A,   // zi8 [8192][1024]
    const unsigned char* __restrict__ Bm,  // zj8 [8192][1024]
    float* __restrict__ rp, float* __restrict__ cp, float* __restrict__ dg) {
    __shared__ unsigned char bA0[16384], bB0[16384], bA1[16384], bB1[16384];
    __shared__ float rbuf[2][128];
    __shared__ float cbuf[2][128];

    // L2-supertile swizzle (R10): XCD = bid&7 (round-robin dispatch).
    // XCD c owns bi in [8c,8c+8); within-XCD sequence q runs 8 temporal
    // supertiles (s) of 64 blocks = 8bi x 8bj -> 2MB working set per
    // co-resident generation. Bijective: q = (bj>>3)*64 + (bi&7)*8 + (bj&7).
    const int c_x = blockIdx.x & 7;
    const int q = blockIdx.x >> 3;           // 0..511
    const int s = q >> 6;                    // supertile 0..7 (temporal)
    const int p = q & 63;                    // position in 8x8 supertile
    const int bi = c_x * 8 + (p >> 3);       // 0..63
    const int bj = s * 8 + (p & 7);          // 0..63
    const int tid = threadIdx.x;
    const int l = tid & 63, w = tid >> 6;
    const int wm = w >> 1, wn = w & 1;       // 2x2 wave grid, per-wave 64x64
    const int llo = l & 15, khi = l >> 4;

    f32x4 acc[4][4] = {};

    const unsigned char* Ag = A + (size_t)(bi * 128) * 1024;
    const unsigned char* Bg = Bm + (size_t)(bj * 128) * 1024;

    // per-thread staging offsets (4 sweeps x 256 thr x 16B = one [128][128B] buf)
    int srow[4], soff[4];
    #pragma unroll
    for (int ss2 = 0; ss2 < 4; ++ss2) {
        int idx = ss2 * 256 + tid;
        srow[ss2] = idx >> 3;
        int clog = idx & 7;
        soff[ss2] = srow[ss2] * 1024 + ((clog ^ (srow[ss2] & 7)) * 16);
    }
    const int ldst = tid * 16;   // linear dest within each sweep block

#define STAGE(ktB, bufA, bufB)                                            \
    _Pragma("unroll") for (int u = 0; u < 4; ++u)                         \
        async16(Ag + (ktB) + soff[u], (bufA) + u * 4096 + ldst);          \
    _Pragma("unroll") for (int u = 0; u < 4; ++u)                         \
        async16(Bg + (ktB) + soff[u], (bufB) + u * 4096 + ldst);

    // prologue: stage tiles 0,1; wait tile 0 (tile1's 8 outstanding)
    STAGE(0, bA0, bB0)
    STAGE(128, bA1, bB1)
    asm volatile("s_waitcnt vmcnt(8)" ::: "memory");
    __builtin_amdgcn_s_barrier();
    __builtin_amdgcn_sched_barrier(0);

    for (int t = 0; t < 8; ++t) {
        const unsigned char* Ac = (t & 1) ? bA1 : bA0;
        const unsigned char* Bc = (t & 1) ? bB1 : bB0;
        unsigned char* Asg = (t & 1) ? bA1 : bA0;
        unsigned char* Bsg = (t & 1) ? bB1 : bB0;

        i32x8 af[4], bfr[4];
        #pragma unroll
        for (int m = 0; m < 4; ++m)
            af[m] = ldfrag(Ac, wm * 64 + m * 16 + llo, khi);
        #pragma unroll
        for (int n = 0; n < 4; ++n)
            bfr[n] = ldfrag(Bc, wn * 64 + n * 16 + llo, khi);
        #pragma unroll
        for (int m = 0; m < 4; ++m)
            #pragma unroll
            for (int n = 0; n < 4; ++n)
                acc[m][n] = __builtin_amdgcn_mfma_scale_f32_16x16x128_f8f6f4(
                    af[m], bfr[n], acc[m][n], 0, 0, 0, USCL, 0, USCL);

        asm volatile("s_waitcnt lgkmcnt(0)" ::: "memory");
        __builtin_amdgcn_s_barrier();        // all waves done reading this buf
        if (t <= 5) {
            STAGE((t + 2) * 128, Asg, Bsg)
            asm volatile("s_waitcnt vmcnt(8)" ::: "memory");   // t+1 landed
        } else if (t == 6) {
            asm volatile("s_waitcnt vmcnt(0)" ::: "memory");   // t=7 landed
        }
        if (t <= 6) {
            __builtin_amdgcn_s_barrier();
            __builtin_amdgcn_sched_barrier(0);
        }
    }
#undef STAGE

    // ---- epilogue (R1-verified 16x16 C/D mapping: col=llo, row=khi*4+reg) ----
    if (bi == bj && wm == wn) {
        #pragma unroll
        for (int m = 0; m < 4; ++m)
            #pragma unroll
            for (int r = 0; r < 4; ++r)
                if (khi * 4 + r == llo)
                    dg[bi * 128 + wm * 64 + m * 16 + llo] = acc[m][m][r];
    }

    #pragma unroll
    for (int m = 0; m < 4; ++m)
        #pragma unroll
        for (int n = 0; n < 4; ++n)
            #pragma unroll
            for (int r = 0; r < 4; ++r)
                acc[m][n][r] = exp2f(acc[m][n][r] * 1.44269504f);

    // row sums over this wave's 64 cols
    #pragma unroll
    for (int m = 0; m < 4; ++m) {
        #pragma unroll
        for (int r = 0; r < 4; ++r) {
            float v = acc[m][0][r] + acc[m][1][r] + acc[m][2][r] + acc[m][3][r];
            v += __shfl_xor(v, 1);
            v += __shfl_xor(v, 2);
            v += __shfl_xor(v, 4);
            v += __shfl_xor(v, 8);
            if (llo == 0) rbuf[wn][wm * 64 + m * 16 + khi * 4 + r] = v;
        }
    }
    // col sums over this wave's 64 rows
    #pragma unroll
    for (int n = 0; n < 4; ++n) {
        float v = 0.f;
        #pragma unroll
        for (int m = 0; m < 4; ++m)
            v += acc[m][n][0] + acc[m][n][1] + acc[m][n][2] + acc[m][n][3];
        v += __shfl_xor(v, 16);
        v += __shfl_xor(v, 32);
        if (khi == 0) cbuf[wm][wn * 64 + n * 16 + llo] = v;
    }
    __syncthreads();
    if (tid < 128) {
        rp[(size_t)bj * 8192 + bi * 128 + tid] = rbuf[0][tid] + rbuf[1][tid];
        cp[(size_t)bi * 8192 + bj * 128 + tid] = cbuf[0][tid] + cbuf[1][tid];
    }
}

// ---- per-row logs, block partial sums ----
__global__ __launch_bounds__(256) void clip_fin1_k(const float* __restrict__ rp,
                                                   const float* __restrict__ cp,
                                                   const float* __restrict__ dg,
                                                   float* __restrict__ part) {
    int i = blockIdx.x * 256 + threadIdx.x;
    float rs = 0.f, cs = 0.f;
    #pragma unroll 8
    for (int b = 0; b < 64; ++b) rs += rp[(size_t)b * 8192 + i];
    #pragma unroll 8
    for (int b = 0; b < 64; ++b) cs += cp[(size_t)b * 8192 + i];
    float c = 0.5f * (logf(rs) + logf(cs)) - dg[i];
    #pragma unroll
    for (int o = 1; o < 64; o <<= 1) c += __shfl_xor(c, o);
    __shared__ float sb[4];
    if ((threadIdx.x & 63) == 0) sb[threadIdx.x >> 6] = c;
    __syncthreads();
    if (threadIdx.x == 0) part[blockIdx.x] = sb[0] + sb[1] + sb[2] + sb[3];
}

__global__ void clip_fin2_k(const float* __restrict__ part, float* __restrict__ out) {
    float v = (threadIdx.x < 32) ? part[threadIdx.x] : 0.f;
    #pragma unroll
    for (int o = 1; o < 64; o <<= 1) v += __shfl_xor(v, o);
    if (threadIdx.x == 0) out[0] = v * (1.f / 8192.f);
}

extern "C" void kernel_launch(void* const* d_in, const int* in_sizes, int n_in,
                              void* d_out, int out_size, void* d_ws, size_t ws_size,
                              hipStream_t stream) {
    const float* zi = (const float*)d_in[0];
    const float* zj = (const float*)d_in[1];
    float* out = (float*)d_out;
    char* ws = (char*)d_ws;

    unsigned int* zi8 = (unsigned int*)(ws);
    unsigned int* zj8 = (unsigned int*)(ws + (size_t)8 * 1024 * 1024);
    float* rp   = (float*)(ws + (size_t)16 * 1024 * 1024);   // 2 MB (64 panels)
    float* cp   = (float*)(ws + (size_t)18 * 1024 * 1024);   // 2 MB (64 panels)
    float* dg   = (float*)(ws + (size_t)20 * 1024 * 1024);
    float* part = (float*)(ws + (size_t)20 * 1024 * 1024 + 32768);

    clip_norm_k<<<8192, 256, 0, stream>>>(zi, zi8, 2.0f);   // temp x2 folded into zi
    clip_norm_k<<<8192, 256, 0, stream>>>(zj, zj8, 1.0f);
    clip_gemm_k<<<4096, 256, 0, stream>>>((const unsigned char*)zi8,
                                          (const unsigned char*)zj8, rp, cp, dg);
    clip_fin1_k<<<32, 256, 0, stream>>>(rp, cp, dg, part);
    clip_fin2_k<<<1, 64, 0, stream>>>(part, out);
}